// Round 1
// 260.173 us; speedup vs baseline: 1.0408x; 1.0408x over previous
//
#include <hip/hip_runtime.h>

// Shapes fixed by setup_inputs():
#define BB    8
#define CF    256
#define HF    128
#define WF    128
#define HLBL  512
#define WLBL  512
#define COLD  16
#define NCLS  21
#define PSTR  260   // padded LDS stride (multiple of 4 -> 16B-aligned rows);
                    // bank = (4*id + c) % 32, reads are ~all broadcast (id==0 dominant)

// ws layout (floats): [0..16) class sums, [16..32) class counts

__global__ __launch_bounds__(256) void proto_loss_main(
    const float* __restrict__ outputs_old,   // [B, COLD, HL, WL]
    const float* __restrict__ features,      // [B, CF, HF, WF]
    const int*   __restrict__ labels,        // [B, HL, WL]
    const float* __restrict__ prototypes,    // [NCLS, CF]
    float* __restrict__ gbins)               // sums[16], counts[16]
{
    // ids = argmax over COLD=16 channels -> ids in [0,16). Only 16 proto rows needed.
    __shared__ float sproto[COLD * PSTR];    // 16*260*4 = 16.25 KB
    __shared__ float spartial[8][WF];        // 4 KB
    __shared__ int   sids[WF];
    __shared__ float ssum[16];
    __shared__ float scnt[16];

    const int t   = threadIdx.x;
    const int blk = blockIdx.x;              // 0 .. B*HF-1
    const int b   = blk >> 7;                // / HF
    const int h   = blk & (HF - 1);          // % HF

    // stage prototype rows 0..15 as float4 (1024 float4 / 256 threads = 4 each)
    #pragma unroll
    for (int i = t; i < COLD * (CF / 4); i += 256) {
        const int r  = i >> 6;               // / (CF/4)
        const int c4 = (i & 63) << 2;
        *(float4*)&sproto[r * PSTR + c4] =
            *(const float4*)&prototypes[r * CF + c4];
    }
    if (t < 16) { ssum[t] = 0.0f; scnt[t] = 0.0f; }

    // per-pixel pseudo-class ids (nearest-down: src = (4h, 4w))
    if (t < WF) {
        const int w = t;
        int id = 0;
        const int lab = labels[(b * HLBL + h * 4) * WLBL + w * 4];
        if (lab == 0) {
            const float* po = outputs_old
                + ((size_t)b * COLD * HLBL + (size_t)h * 4) * WLBL + w * 4;
            float best = po[0];
            #pragma unroll
            for (int c = 1; c < COLD; ++c) {
                float v = po[(size_t)c * HLBL * WLBL];
                if (v > best) { best = v; id = c; }   // strict >: first-max tie-break
            }
        }
        sids[w] = id;
    }
    __syncthreads();

    // Phase 2: float4 feature loads. thread -> 4 consecutive w, 8 c-slices/iter.
    // Class-0 bin is dropped by the reference (per_class[1:]), so threads whose
    // 4 pixels are ALL id==0 contribute nothing -> skip their loads entirely.
    // Exec-masked lanes issue no VMEM; fetched feature lines drop to the
    // fraction of 64B lines containing at least one active pixel.
    const int w4    = (t & 31) * 4;
    const int c_off = t >> 5;                // 0..7
    const int id0 = sids[w4 + 0];
    const int id1 = sids[w4 + 1];
    const int id2 = sids[w4 + 2];
    const int id3 = sids[w4 + 3];

    float a0 = 0.f, a1 = 0.f, a2 = 0.f, a3 = 0.f;
    if ((id0 | id1 | id2 | id3) != 0) {
        const float* pr0 = &sproto[id0 * PSTR];
        const float* pr1 = &sproto[id1 * PSTR];
        const float* pr2 = &sproto[id2 * PSTR];
        const float* pr3 = &sproto[id3 * PSTR];
        const float* fbase = features + ((size_t)b * CF * HF + h) * WF + w4;

        #pragma unroll 8
        for (int k = 0; k < 32; ++k) {
            const int c = k * 8 + c_off;
            const float4 f = *(const float4*)(fbase + (size_t)c * (HF * WF));
            float d0 = f.x - pr0[c]; a0 += d0 * d0;
            float d1 = f.y - pr1[c]; a1 += d1 * d1;
            float d2 = f.z - pr2[c]; a2 += d2 * d2;
            float d3 = f.w - pr3[c]; a3 += d3 * d3;
        }
    }
    spartial[c_off][w4 + 0] = a0;
    spartial[c_off][w4 + 1] = a1;
    spartial[c_off][w4 + 2] = a2;
    spartial[c_off][w4 + 3] = a3;
    __syncthreads();

    // Phase 3: per-pixel value -> per-class LDS bins (id==0 never read by final)
    if (t < WF) {
        const int id = sids[t];
        if (id != 0) {
            float pp = 0.f;
            #pragma unroll
            for (int co = 0; co < 8; ++co) pp += spartial[co][t];
            pp *= (1.0f / CF);
            atomicAdd(&ssum[id], pp);
            atomicAdd(&scnt[id], 1.0f);
        }
    }
    __syncthreads();

    if (t < 16) {
        if (scnt[t] > 0.f) {
            atomicAdd(&gbins[t],      ssum[t]);
            atomicAdd(&gbins[16 + t], scnt[t]);
        }
    }
}

__global__ void proto_loss_final(const float* __restrict__ gbins,
                                 const int* __restrict__ classes_old,
                                 const int* __restrict__ inc_step,
                                 float* __restrict__ out)
{
    if (threadIdx.x == 0 && blockIdx.x == 0) {
        float r = 0.0f;
        if (*inc_step != 0) {
            int K = *classes_old;
            if (K > 16) K = 16;
            for (int id = 1; id < K; ++id) {
                float cnt = gbins[16 + id];
                if (cnt > 0.f) r += gbins[id] / cnt;
            }
        }
        out[0] = r;
    }
}

extern "C" void kernel_launch(void* const* d_in, const int* in_sizes, int n_in,
                              void* d_out, int out_size, void* d_ws, size_t ws_size,
                              hipStream_t stream)
{
    const float* outputs_old = (const float*)d_in[1];
    const float* features    = (const float*)d_in[2];
    const int*   labels      = (const int*)d_in[4];
    const float* prototypes  = (const float*)d_in[5];
    const int*   classes_old = (const int*)d_in[6];
    const int*   inc_step    = (const int*)d_in[7];

    float* gbins = (float*)d_ws;   // 32 floats

    hipMemsetAsync(gbins, 0, 32 * sizeof(float), stream);

    dim3 grid(BB * HF);
    dim3 block(256);
    proto_loss_main<<<grid, block, 0, stream>>>(outputs_old, features, labels,
                                                prototypes, gbins);
    proto_loss_final<<<1, 64, 0, stream>>>(gbins, classes_old, inc_step,
                                           (float*)d_out);
}